// Round 5
// baseline (2676.872 us; speedup 1.0000x reference)
//
#include <hip/hip_runtime.h>
#include <math.h>

// Problem constants (from reference setup_inputs): B=4, C=32, H=W=256
#define B_N 4
#define C_N 32
#define H_N 256
#define W_N 256
#define PI_D 3.14159265358979323846
#define LSQ 257  // float2 stride per sequence region in LDS

__device__ __forceinline__ float2 cmul(float2 a, float2 b) {
    return make_float2(a.x * b.x - a.y * b.y, a.x * b.y + a.y * b.x);
}
__device__ __forceinline__ float2 f2add(float2 a, float2 b) {
    return make_float2(a.x + b.x, a.y + b.y);
}
__device__ __forceinline__ float2 f2sub(float2 a, float2 b) {
    return make_float2(a.x - b.x, a.y - b.y);
}

// ---------------- K0: tables -------------------------------------------------
__global__ void chirp_init(const float* __restrict__ alpha_p,
                           float2* __restrict__ c1, float2* __restrict__ c2,
                           float2* __restrict__ twm, float* __restrict__ scl) {
    int j = threadIdx.x;  // 0..255
    double a = fmin(fmax((double)alpha_p[0], 1e-4), 2.0 - 1e-4);
    double tan_a2 = tan(a * PI_D / 4.0);
    double sin_a  = sin(a * PI_D / 2.0);   // > 0 for a in (0,2)
    double n = (double)(j - 128);
    float sn, cs;

    double u1 = n * n * tan_a2 * (1.0 / 256.0);       // phase = -pi*u1
    u1 -= 2.0 * floor(u1 * 0.5);                      // mod 2
    __sincosf((float)(-PI_D * u1), &sn, &cs);
    c1[j] = make_float2(cs, sn);

    double u2 = n * n / (256.0 * sin_a);
    u2 -= 2.0 * floor(u2 * 0.5);
    __sincosf((float)(-PI_D * u2), &sn, &cs);
    c2[j] = make_float2(cs, sn);

    int k1 = j >> 4, t = j & 15;
    __sincosf((float)(-2.0 * PI_D * (double)(t * k1) / 256.0), &sn, &cs);
    twm[j] = make_float2(cs, sn);

    if (j == 0) scl[0] = (float)(1.0 / sqrt(fabs(sin_a) + 1e-12));
}

// ---------------- FFT16 in registers (radix-4 x radix-4) ---------------------
// Input: v[n] natural order. Output: v[4*(k&3) + (k>>2)] = F[k].
template <bool INV>
__device__ __forceinline__ void fft16(float2* v) {
    const float C1 = 0.9238795325112867f, S1 = 0.3826834323650898f;
    const float C2 = 0.7071067811865476f;
    const float2 tw1 = make_float2(C1, INV ? S1 : -S1);
    const float2 tw2 = make_float2(C2, INV ? C2 : -C2);
    const float2 tw3 = make_float2(S1, INV ? C1 : -C1);
    const float2 tw4 = make_float2(0.0f, INV ? 1.0f : -1.0f);
    const float2 tw6 = make_float2(-C2, INV ? C2 : -C2);
    const float2 tw9 = make_float2(-C1, INV ? -S1 : S1);
    float2 u[16];
    #pragma unroll
    for (int n2 = 0; n2 < 4; ++n2) {
        float2 e0 = v[n2], e1 = v[4 + n2], e2 = v[8 + n2], e3 = v[12 + n2];
        float2 t0 = f2add(e0, e2), t1 = f2sub(e0, e2);
        float2 t2 = f2add(e1, e3), t3 = f2sub(e1, e3);
        float2 A0 = f2add(t0, t2);
        float2 A2 = f2sub(t0, t2);
        float2 A1, A3;
        if (!INV) { A1 = make_float2(t1.x + t3.y, t1.y - t3.x);
                    A3 = make_float2(t1.x - t3.y, t1.y + t3.x); }
        else      { A1 = make_float2(t1.x - t3.y, t1.y + t3.x);
                    A3 = make_float2(t1.x + t3.y, t1.y - t3.x); }
        u[n2] = A0;
        if (n2 == 0) { u[4 + n2] = A1;            u[8 + n2] = A2;            u[12 + n2] = A3; }
        if (n2 == 1) { u[4 + n2] = cmul(A1, tw1); u[8 + n2] = cmul(A2, tw2); u[12 + n2] = cmul(A3, tw3); }
        if (n2 == 2) { u[4 + n2] = cmul(A1, tw2); u[8 + n2] = cmul(A2, tw4); u[12 + n2] = cmul(A3, tw6); }
        if (n2 == 3) { u[4 + n2] = cmul(A1, tw3); u[8 + n2] = cmul(A2, tw6); u[12 + n2] = cmul(A3, tw9); }
    }
    #pragma unroll
    for (int k1 = 0; k1 < 4; ++k1) {
        float2 e0 = u[4 * k1], e1 = u[4 * k1 + 1], e2 = u[4 * k1 + 2], e3 = u[4 * k1 + 3];
        float2 t0 = f2add(e0, e2), t1 = f2sub(e0, e2);
        float2 t2 = f2add(e1, e3), t3 = f2sub(e1, e3);
        v[4 * k1 + 0] = f2add(t0, t2);
        v[4 * k1 + 2] = f2sub(t0, t2);
        if (!INV) { v[4 * k1 + 1] = make_float2(t1.x + t3.y, t1.y - t3.x);
                    v[4 * k1 + 3] = make_float2(t1.x - t3.y, t1.y + t3.x); }
        else      { v[4 * k1 + 1] = make_float2(t1.x - t3.y, t1.y + t3.x);
                    v[4 * k1 + 3] = make_float2(t1.x + t3.y, t1.y - t3.x); }
    }
}
#define REG(k) (4 * ((k) & 3) + ((k) >> 2))

// ---------------- FRFT core: 256-pt via four-step radix-16 -------------------
// In: v[n1] = x[16*n1 + t] * c1[16*n1 + t]. Out: v[REG(m1)] = z[16*m1 + t],
// z = ifft( fft(x*c1) * c2 ) * 256 (caller applies 1/256 in scale).
// sp: this sequence's 16x16 LDS matrix (XOR swizzle: (r,c) at sp[16r + (c^r)]).
__device__ __forceinline__ void frft_core16(float2* v, float2* __restrict__ sp,
                                            int t,
                                            const float2* __restrict__ c2l,
                                            const float2* __restrict__ twl) {
    fft16<false>(v);  // over n1 -> A[k1] at v[REG(k1)]
    float2 w[16];
    #pragma unroll
    for (int k1 = 0; k1 < 16; ++k1)
        w[k1] = cmul(v[REG(k1)], twl[16 * k1 + t]);   // * W256^{t*k1}
    #pragma unroll
    for (int k1 = 0; k1 < 16; ++k1)
        sp[16 * k1 + (t ^ k1)] = w[k1];               // M[k1][t]
    __syncthreads();
    #pragma unroll
    for (int n2 = 0; n2 < 16; ++n2)
        v[n2] = sp[16 * t + (n2 ^ t)];                // M[t][n2]
    fft16<false>(v);  // over n2 -> B[k2] = X[t + 16*k2] at v[REG(k2)]
    #pragma unroll
    for (int k2 = 0; k2 < 16; ++k2)
        w[k2] = cmul(v[REG(k2)], c2l[t + 16 * k2]);   // mid: * c2
    fft16<true>(w);   // over k2 -> C[m2] at w[REG(m2)]
    __syncthreads();  // all phase-1 reads done before overwrite
    #pragma unroll
    for (int m2 = 0; m2 < 16; ++m2) {
        float2 tw = twl[16 * m2 + t];
        tw.y = -tw.y;                                 // W256^{+t*m2}
        sp[16 * m2 + (t ^ m2)] = cmul(w[REG(m2)], tw);
    }
    __syncthreads();
    #pragma unroll
    for (int k1 = 0; k1 < 16; ++k1)
        v[k1] = sp[16 * t + (k1 ^ t)];
    fft16<true>(v);   // over k1 -> z[16*m1 + t] at v[REG(m1)]
}

// ---------------- K1: FRFT along H on REAL input x -> Y ----------------------
// 16 columns per block, 256 threads. seqc = column-in-tile, t = element group.
__global__ __launch_bounds__(256) void frft_cols_real(
        const float* __restrict__ x,
        const float2* __restrict__ c1, const float2* __restrict__ c2,
        const float2* __restrict__ twm, const float* __restrict__ scl,
        float2* __restrict__ Y) {
    __shared__ float2 s[16 * LSQ];
    __shared__ float2 c1l[256], c2l[256], twl[256];
    int tid = threadIdx.x;
    int seqc = tid & 15, t = tid >> 4;
    c1l[tid] = c1[tid]; c2l[tid] = c2[tid]; twl[tid] = twm[tid];

    int blk = blockIdx.x;
    int w0 = (blk & 15) << 4;
    long long bc = blk >> 4;
    const float* xb = x + (bc << 16) + w0 + seqc;
    float2* Yb = Y + (bc << 16) + w0 + seqc;

    float xs[16];
    #pragma unroll
    for (int n1 = 0; n1 < 16; ++n1)
        xs[n1] = xb[(16 * (n1 ^ 8) + t) * W_N];  // ifftshift along H
    __syncthreads();

    float2 v[16];
    #pragma unroll
    for (int n1 = 0; n1 < 16; ++n1) {
        float2 c = c1l[16 * n1 + t];
        v[n1] = make_float2(xs[n1] * c.x, xs[n1] * c.y);
    }

    frft_core16(v, s + seqc * LSQ, t, c2l, twl);

    float sc = scl[0] * (1.0f / 256.0f);
    #pragma unroll
    for (int m1 = 0; m1 < 16; ++m1) {
        float2 o = cmul(v[REG(m1)], c1l[16 * m1 + t]);
        Yb[(16 * (m1 ^ 8) + t) * W_N] = make_float2(o.x * sc, o.y * sc);  // fftshift
    }
}

// ---------------- K2: FRFT along W fused with mag/ang + 1x1 conv -------------
// One block per (b,h): 512 threads = 32 channels x 16 element-groups.
// Transformed rows for all 32 channels kept in LDS, then conv per pixel.
__device__ __forceinline__ float fast_atan2(float y, float x) {
    float ax = fabsf(x), ay = fabsf(y);
    float mx = fmaxf(ax, ay), mn = fminf(ax, ay);
    float z = mn * __builtin_amdgcn_rcpf(fmaxf(mx, 1e-37f));
    float z2 = z * z;
    float p = fmaf(z2, -0.01172120f, 0.05265332f);
    p = fmaf(z2, p, -0.11643287f);
    p = fmaf(z2, p, 0.19354346f);
    p = fmaf(z2, p, -0.33262347f);
    p = fmaf(z2, p, 0.99997726f);
    p = p * z;
    float r = (ay > ax) ? (1.5707963f - p) : p;
    r = (x < 0.0f) ? (3.14159265f - r) : r;
    return copysignf(r, y);
}

__global__ __launch_bounds__(512, 4) void frft_rows_conv(
        const float2* __restrict__ Y,
        const float2* __restrict__ c1, const float2* __restrict__ c2,
        const float2* __restrict__ twm, const float* __restrict__ scl,
        const float* __restrict__ wmat, float* __restrict__ out) {
    __shared__ float2 s[32 * LSQ];   // 32 channel regions, also final row buffer
    __shared__ float2 c1l[256], c2l[256], twl[256];
    int tid = threadIdx.x;
    int t = tid & 15, ch = tid >> 4;  // ch = 0..31; sequence threads = one wave chunk
    if (tid < 256) { c1l[tid] = c1[tid]; c2l[tid] = c2[tid]; twl[tid] = twm[tid]; }

    int b = blockIdx.x >> 8, h = blockIdx.x & 255;
    const float2* xr = Y + (((long long)(b * C_N + ch)) << 16) + (h << 8);

    float2 v[16];
    #pragma unroll
    for (int n1 = 0; n1 < 16; ++n1)
        v[n1] = xr[16 * (n1 ^ 8) + t];   // ifftshift along W
    __syncthreads();   // tables ready

    #pragma unroll
    for (int n1 = 0; n1 < 16; ++n1)
        v[n1] = cmul(v[n1], c1l[16 * n1 + t]);

    float2* sp = s + ch * LSQ;
    frft_core16(v, sp, t, c2l, twl);

    // write final Y row values into own region (natural w order, fftshifted);
    // same-wave WAR with core's final reads -> safe without barrier.
    float sc = scl[0] * (1.0f / 256.0f);
    #pragma unroll
    for (int m1 = 0; m1 < 16; ++m1) {
        float2 o = cmul(v[REG(m1)], c1l[16 * m1 + t]);
        sp[16 * (m1 ^ 8) + t] = make_float2(o.x * sc, o.y * sc);
    }
    __syncthreads();

    // ---- conv phase: thread (w, half) computes 16 output channels ----
    int w = tid & 255;
    float mag[C_N], ang[C_N];
    #pragma unroll
    for (int c = 0; c < C_N; ++c) {
        float2 yv = s[c * LSQ + w];
        mag[c] = sqrtf(fmaf(yv.x, yv.x, yv.y * yv.y));
        ang[c] = fast_atan2(yv.y, yv.x) * 0.31830988618f;  // 1/pi
    }

    float* ob = out + (((long long)(b * C_N)) << 16) + (h << 8) + w;
    if (tid < 256) {
        #pragma unroll
        for (int o = 0; o < 16; ++o) {
            float acc = 0.0f;
            #pragma unroll
            for (int c = 0; c < C_N; ++c) {
                acc = fmaf(wmat[o * 64 + c], mag[c], acc);
                acc = fmaf(wmat[o * 64 + 32 + c], ang[c], acc);
            }
            ob[(long long)o << 16] = acc;
        }
    } else {
        #pragma unroll
        for (int o = 16; o < 32; ++o) {
            float acc = 0.0f;
            #pragma unroll
            for (int c = 0; c < C_N; ++c) {
                acc = fmaf(wmat[o * 64 + c], mag[c], acc);
                acc = fmaf(wmat[o * 64 + 32 + c], ang[c], acc);
            }
            ob[(long long)o << 16] = acc;
        }
    }
}

// ---------------- launch -----------------------------------------------------
extern "C" void kernel_launch(void* const* d_in, const int* in_sizes, int n_in,
                              void* d_out, int out_size, void* d_ws, size_t ws_size,
                              hipStream_t stream) {
    const float* x     = (const float*)d_in[0];
    const float* alpha = (const float*)d_in[1];
    const float* wmat  = (const float*)d_in[2];
    float* out = (float*)d_out;

    char* ws = (char*)d_ws;
    float2* c1  = (float2*)(ws);           // 2048 B
    float2* c2  = (float2*)(ws + 2048);    // 2048 B
    float2* twm = (float2*)(ws + 4096);    // 2048 B
    float*  scl = (float*)(ws + 6144);     // 4 B
    float2* Y   = (float2*)(ws + 8192);    // 64 MiB intermediate (H-pass output)

    chirp_init<<<1, 256, 0, stream>>>(alpha, c1, c2, twm, scl);

    // Pass 1: FRFT along H on real input (order commutes with W pass).
    frft_cols_real<<<B_N * C_N * (W_N / 16), 256, 0, stream>>>(x, c1, c2, twm, scl, Y);

    // Pass 2: FRFT along W + magnitude/phase + 1x1 conv, fused per (b,h).
    frft_rows_conv<<<B_N * H_N, 512, 0, stream>>>(Y, c1, c2, twm, scl, wmat, out);
}

// Round 6
// 188.668 us; speedup vs baseline: 14.1883x; 14.1883x over previous
//
#include <hip/hip_runtime.h>
#include <math.h>

// Problem constants (from reference setup_inputs): B=4, C=32, H=W=256
#define B_N 4
#define C_N 32
#define H_N 256
#define W_N 256
#define PI_D 3.14159265358979323846
#define LSQ 257  // float2 stride per sequence region in LDS

__device__ __forceinline__ float2 cmul(float2 a, float2 b) {
    return make_float2(a.x * b.x - a.y * b.y, a.x * b.y + a.y * b.x);
}
__device__ __forceinline__ float2 f2add(float2 a, float2 b) {
    return make_float2(a.x + b.x, a.y + b.y);
}
__device__ __forceinline__ float2 f2sub(float2 a, float2 b) {
    return make_float2(a.x - b.x, a.y - b.y);
}

// ---------------- K0: tables -------------------------------------------------
__global__ void chirp_init(const float* __restrict__ alpha_p,
                           float2* __restrict__ c1, float2* __restrict__ c2,
                           float2* __restrict__ twm, float* __restrict__ scl) {
    int j = threadIdx.x;  // 0..255
    double a = fmin(fmax((double)alpha_p[0], 1e-4), 2.0 - 1e-4);
    double tan_a2 = tan(a * PI_D / 4.0);
    double sin_a  = sin(a * PI_D / 2.0);   // > 0 for a in (0,2)
    double n = (double)(j - 128);
    float sn, cs;

    double u1 = n * n * tan_a2 * (1.0 / 256.0);       // phase = -pi*u1
    u1 -= 2.0 * floor(u1 * 0.5);                      // mod 2
    __sincosf((float)(-PI_D * u1), &sn, &cs);
    c1[j] = make_float2(cs, sn);

    double u2 = n * n / (256.0 * sin_a);
    u2 -= 2.0 * floor(u2 * 0.5);
    __sincosf((float)(-PI_D * u2), &sn, &cs);
    c2[j] = make_float2(cs, sn);

    int k1 = j >> 4, t = j & 15;
    __sincosf((float)(-2.0 * PI_D * (double)(t * k1) / 256.0), &sn, &cs);
    twm[j] = make_float2(cs, sn);

    if (j == 0) scl[0] = (float)(1.0 / sqrt(fabs(sin_a) + 1e-12));
}

// ---------------- FFT16 in registers (radix-4 x radix-4) ---------------------
// Input: v[n] natural order. Output: v[4*(k&3) + (k>>2)] = F[k].
template <bool INV>
__device__ __forceinline__ void fft16(float2* v) {
    const float C1 = 0.9238795325112867f, S1 = 0.3826834323650898f;
    const float C2 = 0.7071067811865476f;
    const float2 tw1 = make_float2(C1, INV ? S1 : -S1);
    const float2 tw2 = make_float2(C2, INV ? C2 : -C2);
    const float2 tw3 = make_float2(S1, INV ? C1 : -C1);
    const float2 tw4 = make_float2(0.0f, INV ? 1.0f : -1.0f);
    const float2 tw6 = make_float2(-C2, INV ? C2 : -C2);
    const float2 tw9 = make_float2(-C1, INV ? -S1 : S1);
    float2 u[16];
    #pragma unroll
    for (int n2 = 0; n2 < 4; ++n2) {
        float2 e0 = v[n2], e1 = v[4 + n2], e2 = v[8 + n2], e3 = v[12 + n2];
        float2 t0 = f2add(e0, e2), t1 = f2sub(e0, e2);
        float2 t2 = f2add(e1, e3), t3 = f2sub(e1, e3);
        float2 A0 = f2add(t0, t2);
        float2 A2 = f2sub(t0, t2);
        float2 A1, A3;
        if (!INV) { A1 = make_float2(t1.x + t3.y, t1.y - t3.x);
                    A3 = make_float2(t1.x - t3.y, t1.y + t3.x); }
        else      { A1 = make_float2(t1.x - t3.y, t1.y + t3.x);
                    A3 = make_float2(t1.x + t3.y, t1.y - t3.x); }
        u[n2] = A0;
        if (n2 == 0) { u[4 + n2] = A1;            u[8 + n2] = A2;            u[12 + n2] = A3; }
        if (n2 == 1) { u[4 + n2] = cmul(A1, tw1); u[8 + n2] = cmul(A2, tw2); u[12 + n2] = cmul(A3, tw3); }
        if (n2 == 2) { u[4 + n2] = cmul(A1, tw2); u[8 + n2] = cmul(A2, tw4); u[12 + n2] = cmul(A3, tw6); }
        if (n2 == 3) { u[4 + n2] = cmul(A1, tw3); u[8 + n2] = cmul(A2, tw6); u[12 + n2] = cmul(A3, tw9); }
    }
    #pragma unroll
    for (int k1 = 0; k1 < 4; ++k1) {
        float2 e0 = u[4 * k1], e1 = u[4 * k1 + 1], e2 = u[4 * k1 + 2], e3 = u[4 * k1 + 3];
        float2 t0 = f2add(e0, e2), t1 = f2sub(e0, e2);
        float2 t2 = f2add(e1, e3), t3 = f2sub(e1, e3);
        v[4 * k1 + 0] = f2add(t0, t2);
        v[4 * k1 + 2] = f2sub(t0, t2);
        if (!INV) { v[4 * k1 + 1] = make_float2(t1.x + t3.y, t1.y - t3.x);
                    v[4 * k1 + 3] = make_float2(t1.x - t3.y, t1.y + t3.x); }
        else      { v[4 * k1 + 1] = make_float2(t1.x - t3.y, t1.y + t3.x);
                    v[4 * k1 + 3] = make_float2(t1.x + t3.y, t1.y - t3.x); }
    }
}
#define REG(k) (4 * ((k) & 3) + ((k) >> 2))

// ---------------- FRFT core: 256-pt via four-step radix-16 -------------------
// In: v[n1] = x[16*n1 + t] * c1[16*n1 + t]. Out: v[REG(m1)] = z[16*m1 + t],
// z = ifft( fft(x*c1) * c2 ) * 256 (caller applies 1/256 in scale).
// sp: this sequence's 16x16 LDS matrix (XOR swizzle: (r,c) at sp[16r + (c^r)]).
__device__ __forceinline__ void frft_core16(float2* v, float2* __restrict__ sp,
                                            int t,
                                            const float2* __restrict__ c2l,
                                            const float2* __restrict__ twl) {
    fft16<false>(v);  // over n1 -> A[k1] at v[REG(k1)]
    float2 w[16];
    #pragma unroll
    for (int k1 = 0; k1 < 16; ++k1)
        w[k1] = cmul(v[REG(k1)], twl[16 * k1 + t]);   // * W256^{t*k1}
    #pragma unroll
    for (int k1 = 0; k1 < 16; ++k1)
        sp[16 * k1 + (t ^ k1)] = w[k1];               // M[k1][t]
    __syncthreads();
    #pragma unroll
    for (int n2 = 0; n2 < 16; ++n2)
        v[n2] = sp[16 * t + (n2 ^ t)];                // M[t][n2]
    fft16<false>(v);  // over n2 -> B[k2] = X[t + 16*k2] at v[REG(k2)]
    #pragma unroll
    for (int k2 = 0; k2 < 16; ++k2)
        w[k2] = cmul(v[REG(k2)], c2l[t + 16 * k2]);   // mid: * c2
    fft16<true>(w);   // over k2 -> C[m2] at w[REG(m2)]
    __syncthreads();  // all phase-1 reads done before overwrite
    #pragma unroll
    for (int m2 = 0; m2 < 16; ++m2) {
        float2 tw = twl[16 * m2 + t];
        tw.y = -tw.y;                                 // W256^{+t*m2}
        sp[16 * m2 + (t ^ m2)] = cmul(w[REG(m2)], tw);
    }
    __syncthreads();
    #pragma unroll
    for (int k1 = 0; k1 < 16; ++k1)
        v[k1] = sp[16 * t + (k1 ^ t)];
    fft16<true>(v);   // over k1 -> z[16*m1 + t] at v[REG(m1)]
}

// ---------------- K1: FRFT along H on REAL input x -> Y ----------------------
// 16 columns per block, 256 threads. seqc = column-in-tile, t = element group.
__global__ __launch_bounds__(256) void frft_cols_real(
        const float* __restrict__ x,
        const float2* __restrict__ c1, const float2* __restrict__ c2,
        const float2* __restrict__ twm, const float* __restrict__ scl,
        float2* __restrict__ Y) {
    __shared__ float2 s[16 * LSQ];
    __shared__ float2 c1l[256], c2l[256], twl[256];
    int tid = threadIdx.x;
    int seqc = tid & 15, t = tid >> 4;
    c1l[tid] = c1[tid]; c2l[tid] = c2[tid]; twl[tid] = twm[tid];

    int blk = blockIdx.x;
    int w0 = (blk & 15) << 4;
    long long bc = blk >> 4;
    const float* xb = x + (bc << 16) + w0 + seqc;
    float2* Yb = Y + (bc << 16) + w0 + seqc;

    float xs[16];
    #pragma unroll
    for (int n1 = 0; n1 < 16; ++n1)
        xs[n1] = xb[(16 * (n1 ^ 8) + t) * W_N];  // ifftshift along H
    __syncthreads();

    float2 v[16];
    #pragma unroll
    for (int n1 = 0; n1 < 16; ++n1) {
        float2 c = c1l[16 * n1 + t];
        v[n1] = make_float2(xs[n1] * c.x, xs[n1] * c.y);
    }

    frft_core16(v, s + seqc * LSQ, t, c2l, twl);

    float sc = scl[0] * (1.0f / 256.0f);
    #pragma unroll
    for (int m1 = 0; m1 < 16; ++m1) {
        float2 o = cmul(v[REG(m1)], c1l[16 * m1 + t]);
        Yb[(16 * (m1 ^ 8) + t) * W_N] = make_float2(o.x * sc, o.y * sc);  // fftshift
    }
}

// ---------------- K2: FRFT along W fused with mag/ang + 1x1 conv -------------
// One block per (b,h): 512 threads = 32 channels x 16 element-groups.
// Each thread converts its OWN 16 outputs to (mag, ang/pi) at store time, so
// the conv phase needs only 16 accumulators (no mag[32]/ang[32] arrays ->
// no spill; round 5's 64-VGPR scratch spill moved 8 GB of HBM).
__device__ __forceinline__ float fast_atan2(float y, float x) {
    float ax = fabsf(x), ay = fabsf(y);
    float mx = fmaxf(ax, ay), mn = fminf(ax, ay);
    float z = mn * __builtin_amdgcn_rcpf(fmaxf(mx, 1e-37f));
    float z2 = z * z;
    float p = fmaf(z2, -0.01172120f, 0.05265332f);
    p = fmaf(z2, p, -0.11643287f);
    p = fmaf(z2, p, 0.19354346f);
    p = fmaf(z2, p, -0.33262347f);
    p = fmaf(z2, p, 0.99997726f);
    p = p * z;
    float r = (ay > ax) ? (1.5707963f - p) : p;
    r = (x < 0.0f) ? (3.14159265f - r) : r;
    return copysignf(r, y);
}

__global__ __launch_bounds__(512) void frft_rows_conv(
        const float2* __restrict__ Y,
        const float2* __restrict__ c1, const float2* __restrict__ c2,
        const float2* __restrict__ twm, const float* __restrict__ scl,
        const float* __restrict__ wmat, float* __restrict__ out) {
    __shared__ float2 s[32 * LSQ];   // per-channel regions; ends as (mag,ang)
    __shared__ float2 c1l[256], c2l[256], twl[256];
    int tid = threadIdx.x;
    int t = tid & 15, ch = tid >> 4;  // ch = 0..31
    if (tid < 256) { c1l[tid] = c1[tid]; c2l[tid] = c2[tid]; twl[tid] = twm[tid]; }

    int b = blockIdx.x >> 8, h = blockIdx.x & 255;
    const float2* xr = Y + (((long long)(b * C_N + ch)) << 16) + (h << 8);

    float2 v[16];
    #pragma unroll
    for (int n1 = 0; n1 < 16; ++n1)
        v[n1] = xr[16 * (n1 ^ 8) + t];   // ifftshift along W
    __syncthreads();   // tables ready

    #pragma unroll
    for (int n1 = 0; n1 < 16; ++n1)
        v[n1] = cmul(v[n1], c1l[16 * n1 + t]);

    float2* sp = s + ch * LSQ;
    frft_core16(v, sp, t, c2l, twl);

    // Store (mag, ang/pi) directly: same-thread WAR with core's final reads.
    float sc = scl[0] * (1.0f / 256.0f);
    #pragma unroll
    for (int m1 = 0; m1 < 16; ++m1) {
        float2 o = cmul(v[REG(m1)], c1l[16 * m1 + t]);
        float mg = sc * sqrtf(fmaf(o.x, o.x, o.y * o.y));
        float an = fast_atan2(o.y, o.x) * 0.31830988618f;  // angle unaffected by sc>0
        sp[16 * (m1 ^ 8) + t] = make_float2(mg, an);       // index = final pixel w
    }
    __syncthreads();

    // ---- conv phase: thread (w, half) computes 16 output channels ----
    int w = tid & 255;
    int obase = (tid >> 8) << 4;  // 0 or 16
    float acc[16];
    #pragma unroll
    for (int o = 0; o < 16; ++o) acc[o] = 0.0f;

    #pragma unroll 4
    for (int c = 0; c < C_N; ++c) {
        float2 yv = s[c * LSQ + w];   // (mag, ang)
        #pragma unroll
        for (int o = 0; o < 16; ++o) {
            acc[o] = fmaf(wmat[(obase + o) * 64 + c], yv.x, acc[o]);
            acc[o] = fmaf(wmat[(obase + o) * 64 + 32 + c], yv.y, acc[o]);
        }
    }

    float* ob = out + (((long long)(b * C_N + obase)) << 16) + (h << 8) + w;
    #pragma unroll
    for (int o = 0; o < 16; ++o)
        ob[(long long)o << 16] = acc[o];
}

// ---------------- launch -----------------------------------------------------
extern "C" void kernel_launch(void* const* d_in, const int* in_sizes, int n_in,
                              void* d_out, int out_size, void* d_ws, size_t ws_size,
                              hipStream_t stream) {
    const float* x     = (const float*)d_in[0];
    const float* alpha = (const float*)d_in[1];
    const float* wmat  = (const float*)d_in[2];
    float* out = (float*)d_out;

    char* ws = (char*)d_ws;
    float2* c1  = (float2*)(ws);           // 2048 B
    float2* c2  = (float2*)(ws + 2048);    // 2048 B
    float2* twm = (float2*)(ws + 4096);    // 2048 B
    float*  scl = (float*)(ws + 6144);     // 4 B
    float2* Y   = (float2*)(ws + 8192);    // 64 MiB intermediate (H-pass output)

    chirp_init<<<1, 256, 0, stream>>>(alpha, c1, c2, twm, scl);

    // Pass 1: FRFT along H on real input (order commutes with W pass).
    frft_cols_real<<<B_N * C_N * (W_N / 16), 256, 0, stream>>>(x, c1, c2, twm, scl, Y);

    // Pass 2: FRFT along W + magnitude/phase + 1x1 conv, fused per (b,h).
    frft_rows_conv<<<B_N * H_N, 512, 0, stream>>>(Y, c1, c2, twm, scl, wmat, out);
}

// Round 7
// 147.507 us; speedup vs baseline: 18.1475x; 1.2790x over previous
//
#include <hip/hip_runtime.h>
#include <math.h>

// Problem constants (from reference setup_inputs): B=4, C=32, H=W=256
#define B_N 4
#define C_N 32
#define H_N 256
#define W_N 256
#define PI_D 3.14159265358979323846
#define LSQ 257  // float2 stride per sequence region in LDS

__device__ __forceinline__ float2 cmul(float2 a, float2 b) {
    return make_float2(a.x * b.x - a.y * b.y, a.x * b.y + a.y * b.x);
}
__device__ __forceinline__ float2 f2add(float2 a, float2 b) {
    return make_float2(a.x + b.x, a.y + b.y);
}
__device__ __forceinline__ float2 f2sub(float2 a, float2 b) {
    return make_float2(a.x - b.x, a.y - b.y);
}

// ---------------- K0: tables -------------------------------------------------
__global__ void chirp_init(const float* __restrict__ alpha_p,
                           float2* __restrict__ c1, float2* __restrict__ c2,
                           float2* __restrict__ twm, float* __restrict__ scl) {
    int j = threadIdx.x;  // 0..255
    double a = fmin(fmax((double)alpha_p[0], 1e-4), 2.0 - 1e-4);
    double tan_a2 = tan(a * PI_D / 4.0);
    double sin_a  = sin(a * PI_D / 2.0);   // > 0 for a in (0,2)
    double n = (double)(j - 128);
    float sn, cs;

    double u1 = n * n * tan_a2 * (1.0 / 256.0);       // phase = -pi*u1
    u1 -= 2.0 * floor(u1 * 0.5);                      // mod 2
    __sincosf((float)(-PI_D * u1), &sn, &cs);
    c1[j] = make_float2(cs, sn);

    double u2 = n * n / (256.0 * sin_a);
    u2 -= 2.0 * floor(u2 * 0.5);
    __sincosf((float)(-PI_D * u2), &sn, &cs);
    c2[j] = make_float2(cs, sn);

    int k1 = j >> 4, t = j & 15;
    __sincosf((float)(-2.0 * PI_D * (double)(t * k1) / 256.0), &sn, &cs);
    twm[j] = make_float2(cs, sn);

    if (j == 0) scl[0] = (float)(1.0 / sqrt(fabs(sin_a) + 1e-12));
}

// ---------------- FFT16 in registers (radix-4 x radix-4) ---------------------
// Input: v[n] natural order. Output: v[4*(k&3) + (k>>2)] = F[k].
template <bool INV>
__device__ __forceinline__ void fft16(float2* v) {
    const float C1 = 0.9238795325112867f, S1 = 0.3826834323650898f;
    const float C2 = 0.7071067811865476f;
    const float2 tw1 = make_float2(C1, INV ? S1 : -S1);
    const float2 tw2 = make_float2(C2, INV ? C2 : -C2);
    const float2 tw3 = make_float2(S1, INV ? C1 : -C1);
    const float2 tw4 = make_float2(0.0f, INV ? 1.0f : -1.0f);
    const float2 tw6 = make_float2(-C2, INV ? C2 : -C2);
    const float2 tw9 = make_float2(-C1, INV ? -S1 : S1);
    float2 u[16];
    #pragma unroll
    for (int n2 = 0; n2 < 4; ++n2) {
        float2 e0 = v[n2], e1 = v[4 + n2], e2 = v[8 + n2], e3 = v[12 + n2];
        float2 t0 = f2add(e0, e2), t1 = f2sub(e0, e2);
        float2 t2 = f2add(e1, e3), t3 = f2sub(e1, e3);
        float2 A0 = f2add(t0, t2);
        float2 A2 = f2sub(t0, t2);
        float2 A1, A3;
        if (!INV) { A1 = make_float2(t1.x + t3.y, t1.y - t3.x);
                    A3 = make_float2(t1.x - t3.y, t1.y + t3.x); }
        else      { A1 = make_float2(t1.x - t3.y, t1.y + t3.x);
                    A3 = make_float2(t1.x + t3.y, t1.y - t3.x); }
        u[n2] = A0;
        if (n2 == 0) { u[4 + n2] = A1;            u[8 + n2] = A2;            u[12 + n2] = A3; }
        if (n2 == 1) { u[4 + n2] = cmul(A1, tw1); u[8 + n2] = cmul(A2, tw2); u[12 + n2] = cmul(A3, tw3); }
        if (n2 == 2) { u[4 + n2] = cmul(A1, tw2); u[8 + n2] = cmul(A2, tw4); u[12 + n2] = cmul(A3, tw6); }
        if (n2 == 3) { u[4 + n2] = cmul(A1, tw3); u[8 + n2] = cmul(A2, tw6); u[12 + n2] = cmul(A3, tw9); }
    }
    #pragma unroll
    for (int k1 = 0; k1 < 4; ++k1) {
        float2 e0 = u[4 * k1], e1 = u[4 * k1 + 1], e2 = u[4 * k1 + 2], e3 = u[4 * k1 + 3];
        float2 t0 = f2add(e0, e2), t1 = f2sub(e0, e2);
        float2 t2 = f2add(e1, e3), t3 = f2sub(e1, e3);
        v[4 * k1 + 0] = f2add(t0, t2);
        v[4 * k1 + 2] = f2sub(t0, t2);
        if (!INV) { v[4 * k1 + 1] = make_float2(t1.x + t3.y, t1.y - t3.x);
                    v[4 * k1 + 3] = make_float2(t1.x - t3.y, t1.y + t3.x); }
        else      { v[4 * k1 + 1] = make_float2(t1.x - t3.y, t1.y + t3.x);
                    v[4 * k1 + 3] = make_float2(t1.x + t3.y, t1.y - t3.x); }
    }
}
#define REG(k) (4 * ((k) & 3) + ((k) >> 2))

// ---------------- FRFT core: 256-pt via four-step radix-16 -------------------
// In: v[n1] = x[16*n1 + t] * c1[16*n1 + t]. Out: v[REG(m1)] = z[16*m1 + t],
// z = ifft( fft(x*c1) * c2 ) * 256 (caller applies 1/256 in scale).
// sp: this sequence's 16x16 LDS matrix (XOR swizzle: (r,c) at sp[16r + (c^r)]).
__device__ __forceinline__ void frft_core16(float2* v, float2* __restrict__ sp,
                                            int t,
                                            const float2* __restrict__ c2l,
                                            const float2* __restrict__ twl) {
    fft16<false>(v);  // over n1 -> A[k1] at v[REG(k1)]
    float2 w[16];
    #pragma unroll
    for (int k1 = 0; k1 < 16; ++k1)
        w[k1] = cmul(v[REG(k1)], twl[16 * k1 + t]);   // * W256^{t*k1}
    #pragma unroll
    for (int k1 = 0; k1 < 16; ++k1)
        sp[16 * k1 + (t ^ k1)] = w[k1];               // M[k1][t]
    __syncthreads();
    #pragma unroll
    for (int n2 = 0; n2 < 16; ++n2)
        v[n2] = sp[16 * t + (n2 ^ t)];                // M[t][n2]
    fft16<false>(v);  // over n2 -> B[k2] = X[t + 16*k2] at v[REG(k2)]
    #pragma unroll
    for (int k2 = 0; k2 < 16; ++k2)
        w[k2] = cmul(v[REG(k2)], c2l[t + 16 * k2]);   // mid: * c2
    fft16<true>(w);   // over k2 -> C[m2] at w[REG(m2)]
    __syncthreads();  // all phase-1 reads done before overwrite
    #pragma unroll
    for (int m2 = 0; m2 < 16; ++m2) {
        float2 tw = twl[16 * m2 + t];
        tw.y = -tw.y;                                 // W256^{+t*m2}
        sp[16 * m2 + (t ^ m2)] = cmul(w[REG(m2)], tw);
    }
    __syncthreads();
    #pragma unroll
    for (int k1 = 0; k1 < 16; ++k1)
        v[k1] = sp[16 * t + (k1 ^ t)];
    fft16<true>(v);   // over k1 -> z[16*m1 + t] at v[REG(m1)]
}

// ---------------- K1: FRFT along H on REAL input x -> Y ----------------------
// 16 columns per block, 256 threads. seqc = column-in-tile, t = element group.
__global__ __launch_bounds__(256) void frft_cols_real(
        const float* __restrict__ x,
        const float2* __restrict__ c1, const float2* __restrict__ c2,
        const float2* __restrict__ twm, const float* __restrict__ scl,
        float2* __restrict__ Y) {
    __shared__ float2 s[16 * LSQ];
    __shared__ float2 c1l[256], c2l[256], twl[256];
    int tid = threadIdx.x;
    int seqc = tid & 15, t = tid >> 4;
    c1l[tid] = c1[tid]; c2l[tid] = c2[tid]; twl[tid] = twm[tid];

    int blk = blockIdx.x;
    int w0 = (blk & 15) << 4;
    long long bc = blk >> 4;
    const float* xb = x + (bc << 16) + w0 + seqc;
    float2* Yb = Y + (bc << 16) + w0 + seqc;

    float xs[16];
    #pragma unroll
    for (int n1 = 0; n1 < 16; ++n1)
        xs[n1] = xb[(16 * (n1 ^ 8) + t) * W_N];  // ifftshift along H
    __syncthreads();

    float2 v[16];
    #pragma unroll
    for (int n1 = 0; n1 < 16; ++n1) {
        float2 c = c1l[16 * n1 + t];
        v[n1] = make_float2(xs[n1] * c.x, xs[n1] * c.y);
    }

    frft_core16(v, s + seqc * LSQ, t, c2l, twl);

    float sc = scl[0] * (1.0f / 256.0f);
    #pragma unroll
    for (int m1 = 0; m1 < 16; ++m1) {
        float2 o = cmul(v[REG(m1)], c1l[16 * m1 + t]);
        Yb[(16 * (m1 ^ 8) + t) * W_N] = make_float2(o.x * sc, o.y * sc);  // fftshift
    }
}

// ---------------- K2: FRFT along W fused with mag/ang + 1x1 conv -------------
// One block per (b,h): 512 threads = 32 channels x 16 element-groups.
// Conv phase: obase forced into an SGPR via readfirstlane so the weight loads
// compile to s_load (scalar pipe). Round 6 left them divergent -> 2048 VMEM
// instructions/thread -> VMEM-pipe bound (117 us at 3.6% HBM).
__device__ __forceinline__ float fast_atan2(float y, float x) {
    float ax = fabsf(x), ay = fabsf(y);
    float mx = fmaxf(ax, ay), mn = fminf(ax, ay);
    float z = mn * __builtin_amdgcn_rcpf(fmaxf(mx, 1e-37f));
    float z2 = z * z;
    float p = fmaf(z2, -0.01172120f, 0.05265332f);
    p = fmaf(z2, p, -0.11643287f);
    p = fmaf(z2, p, 0.19354346f);
    p = fmaf(z2, p, -0.33262347f);
    p = fmaf(z2, p, 0.99997726f);
    p = p * z;
    float r = (ay > ax) ? (1.5707963f - p) : p;
    r = (x < 0.0f) ? (3.14159265f - r) : r;
    return copysignf(r, y);
}

__global__ __launch_bounds__(512) void frft_rows_conv(
        const float2* __restrict__ Y,
        const float2* __restrict__ c1, const float2* __restrict__ c2,
        const float2* __restrict__ twm, const float* __restrict__ scl,
        const float* __restrict__ wmat, float* __restrict__ out) {
    __shared__ float2 s[32 * LSQ];   // per-channel regions; ends as (mag,ang)
    __shared__ float2 c1l[256], c2l[256], twl[256];
    int tid = threadIdx.x;
    int t = tid & 15, ch = tid >> 4;  // ch = 0..31
    if (tid < 256) { c1l[tid] = c1[tid]; c2l[tid] = c2[tid]; twl[tid] = twm[tid]; }

    int b = blockIdx.x >> 8, h = blockIdx.x & 255;
    const float2* xr = Y + (((long long)(b * C_N + ch)) << 16) + (h << 8);

    float2 v[16];
    #pragma unroll
    for (int n1 = 0; n1 < 16; ++n1)
        v[n1] = xr[16 * (n1 ^ 8) + t];   // ifftshift along W
    __syncthreads();   // tables ready

    #pragma unroll
    for (int n1 = 0; n1 < 16; ++n1)
        v[n1] = cmul(v[n1], c1l[16 * n1 + t]);

    float2* sp = s + ch * LSQ;
    frft_core16(v, sp, t, c2l, twl);

    // Store (mag, ang/pi) directly: same-thread WAR with core's final reads.
    float sc = scl[0] * (1.0f / 256.0f);
    #pragma unroll
    for (int m1 = 0; m1 < 16; ++m1) {
        float2 o = cmul(v[REG(m1)], c1l[16 * m1 + t]);
        float mg = sc * sqrtf(fmaf(o.x, o.x, o.y * o.y));
        float an = fast_atan2(o.y, o.x) * 0.31830988618f;  // angle unaffected by sc>0
        sp[16 * (m1 ^ 8) + t] = make_float2(mg, an);       // index = final pixel w
    }
    __syncthreads();

    // ---- conv phase: thread (w, half) computes 16 output channels ----
    int w = tid & 255;
    // wave-uniform by construction (wave=64 threads); force into SGPR so the
    // weight loads become s_load (scalar pipe), not per-lane VMEM.
    int obase = __builtin_amdgcn_readfirstlane((tid >> 8) << 4);  // 0 or 16
    const float* wrow = wmat + obase * 64;

    float acc[16];
    #pragma unroll
    for (int o = 0; o < 16; ++o) acc[o] = 0.0f;

    #pragma unroll 4
    for (int c = 0; c < C_N; ++c) {
        float2 yv = s[c * LSQ + w];   // (mag, ang)
        #pragma unroll
        for (int o = 0; o < 16; ++o) {
            acc[o] = fmaf(wrow[o * 64 + c], yv.x, acc[o]);
            acc[o] = fmaf(wrow[o * 64 + 32 + c], yv.y, acc[o]);
        }
    }

    float* ob = out + (((long long)(b * C_N + obase)) << 16) + (h << 8) + w;
    #pragma unroll
    for (int o = 0; o < 16; ++o)
        ob[(long long)o << 16] = acc[o];
}

// ---------------- launch -----------------------------------------------------
extern "C" void kernel_launch(void* const* d_in, const int* in_sizes, int n_in,
                              void* d_out, int out_size, void* d_ws, size_t ws_size,
                              hipStream_t stream) {
    const float* x     = (const float*)d_in[0];
    const float* alpha = (const float*)d_in[1];
    const float* wmat  = (const float*)d_in[2];
    float* out = (float*)d_out;

    char* ws = (char*)d_ws;
    float2* c1  = (float2*)(ws);           // 2048 B
    float2* c2  = (float2*)(ws + 2048);    // 2048 B
    float2* twm = (float2*)(ws + 4096);    // 2048 B
    float*  scl = (float*)(ws + 6144);     // 4 B
    float2* Y   = (float2*)(ws + 8192);    // 64 MiB intermediate (H-pass output)

    chirp_init<<<1, 256, 0, stream>>>(alpha, c1, c2, twm, scl);

    // Pass 1: FRFT along H on real input (order commutes with W pass).
    frft_cols_real<<<B_N * C_N * (W_N / 16), 256, 0, stream>>>(x, c1, c2, twm, scl, Y);

    // Pass 2: FRFT along W + magnitude/phase + 1x1 conv, fused per (b,h).
    frft_rows_conv<<<B_N * H_N, 512, 0, stream>>>(Y, c1, c2, twm, scl, wmat, out);
}

// Round 8
// 128.648 us; speedup vs baseline: 20.8077x; 1.1466x over previous
//
#include <hip/hip_runtime.h>
#include <math.h>

// Problem constants (from reference setup_inputs): B=4, C=32, H=W=256
#define B_N 4
#define C_N 32
#define H_N 256
#define W_N 256
#define PI_D 3.14159265358979323846
#define LSQ 257   // float2 stride per sequence region in LDS
#define LDW 260   // float stride for out-transpose buffer (reuses s)

typedef _Float16 half8 __attribute__((ext_vector_type(8)));
typedef float f32x4 __attribute__((ext_vector_type(4)));

__device__ __forceinline__ float2 cmul(float2 a, float2 b) {
    return make_float2(a.x * b.x - a.y * b.y, a.x * b.y + a.y * b.x);
}
__device__ __forceinline__ float2 f2add(float2 a, float2 b) {
    return make_float2(a.x + b.x, a.y + b.y);
}
__device__ __forceinline__ float2 f2sub(float2 a, float2 b) {
    return make_float2(a.x - b.x, a.y - b.y);
}

// ---------------- per-block chirp/twiddle tables (replaces chirp_init) -------
__device__ __forceinline__ void make_tables(int tid, const float* __restrict__ alpha_p,
                                            float2* c1l, float2* c2l, float2* twl,
                                            float* sscl) {
    if (tid < 256) {
        int j = tid;
        double a = fmin(fmax((double)alpha_p[0], 1e-4), 2.0 - 1e-4);
        double tan_a2 = tan(a * PI_D / 4.0);
        double sin_a  = sin(a * PI_D / 2.0);   // > 0 for a in (0,2)
        double n = (double)(j - 128);
        float sn, cs;

        double u1 = n * n * tan_a2 * (1.0 / 256.0);   // phase = -pi*u1
        u1 -= 2.0 * floor(u1 * 0.5);                  // mod 2
        __sincosf((float)(-PI_D * u1), &sn, &cs);
        c1l[j] = make_float2(cs, sn);

        double u2 = n * n / (256.0 * sin_a);
        u2 -= 2.0 * floor(u2 * 0.5);
        __sincosf((float)(-PI_D * u2), &sn, &cs);
        c2l[j] = make_float2(cs, sn);

        int k1 = j >> 4, t = j & 15;
        __sincosf((float)(-2.0 * PI_D * (double)(t * k1) * (1.0 / 256.0)), &sn, &cs);
        twl[j] = make_float2(cs, sn);

        if (j == 0) *sscl = (float)(1.0 / sqrt(fabs(sin_a) + 1e-12));
    }
}

// ---------------- FFT16 in registers (radix-4 x radix-4) ---------------------
// Input: v[n] natural order. Output: v[4*(k&3) + (k>>2)] = F[k].
template <bool INV>
__device__ __forceinline__ void fft16(float2* v) {
    const float C1 = 0.9238795325112867f, S1 = 0.3826834323650898f;
    const float C2 = 0.7071067811865476f;
    const float2 tw1 = make_float2(C1, INV ? S1 : -S1);
    const float2 tw2 = make_float2(C2, INV ? C2 : -C2);
    const float2 tw3 = make_float2(S1, INV ? C1 : -C1);
    const float2 tw4 = make_float2(0.0f, INV ? 1.0f : -1.0f);
    const float2 tw6 = make_float2(-C2, INV ? C2 : -C2);
    const float2 tw9 = make_float2(-C1, INV ? -S1 : S1);
    float2 u[16];
    #pragma unroll
    for (int n2 = 0; n2 < 4; ++n2) {
        float2 e0 = v[n2], e1 = v[4 + n2], e2 = v[8 + n2], e3 = v[12 + n2];
        float2 t0 = f2add(e0, e2), t1 = f2sub(e0, e2);
        float2 t2 = f2add(e1, e3), t3 = f2sub(e1, e3);
        float2 A0 = f2add(t0, t2);
        float2 A2 = f2sub(t0, t2);
        float2 A1, A3;
        if (!INV) { A1 = make_float2(t1.x + t3.y, t1.y - t3.x);
                    A3 = make_float2(t1.x - t3.y, t1.y + t3.x); }
        else      { A1 = make_float2(t1.x - t3.y, t1.y + t3.x);
                    A3 = make_float2(t1.x + t3.y, t1.y - t3.x); }
        u[n2] = A0;
        if (n2 == 0) { u[4 + n2] = A1;            u[8 + n2] = A2;            u[12 + n2] = A3; }
        if (n2 == 1) { u[4 + n2] = cmul(A1, tw1); u[8 + n2] = cmul(A2, tw2); u[12 + n2] = cmul(A3, tw3); }
        if (n2 == 2) { u[4 + n2] = cmul(A1, tw2); u[8 + n2] = cmul(A2, tw4); u[12 + n2] = cmul(A3, tw6); }
        if (n2 == 3) { u[4 + n2] = cmul(A1, tw3); u[8 + n2] = cmul(A2, tw6); u[12 + n2] = cmul(A3, tw9); }
    }
    #pragma unroll
    for (int k1 = 0; k1 < 4; ++k1) {
        float2 e0 = u[4 * k1], e1 = u[4 * k1 + 1], e2 = u[4 * k1 + 2], e3 = u[4 * k1 + 3];
        float2 t0 = f2add(e0, e2), t1 = f2sub(e0, e2);
        float2 t2 = f2add(e1, e3), t3 = f2sub(e1, e3);
        v[4 * k1 + 0] = f2add(t0, t2);
        v[4 * k1 + 2] = f2sub(t0, t2);
        if (!INV) { v[4 * k1 + 1] = make_float2(t1.x + t3.y, t1.y - t3.x);
                    v[4 * k1 + 3] = make_float2(t1.x - t3.y, t1.y + t3.x); }
        else      { v[4 * k1 + 1] = make_float2(t1.x - t3.y, t1.y + t3.x);
                    v[4 * k1 + 3] = make_float2(t1.x + t3.y, t1.y - t3.x); }
    }
}
#define REG(k) (4 * ((k) & 3) + ((k) >> 2))

// ---------------- FRFT core: 256-pt via four-step radix-16 -------------------
// In: v[n1] = x[16*n1 + t] * c1[16*n1 + t]. Out: v[REG(m1)] = z[16*m1 + t],
// z = ifft( fft(x*c1) * c2 ) * 256 (caller applies 1/256 in scale).
// sp: this sequence's 16x16 LDS matrix (XOR swizzle: (r,c) at sp[16r + (c^r)]).
__device__ __forceinline__ void frft_core16(float2* v, float2* __restrict__ sp,
                                            int t,
                                            const float2* __restrict__ c2l,
                                            const float2* __restrict__ twl) {
    fft16<false>(v);  // over n1 -> A[k1] at v[REG(k1)]
    float2 w[16];
    #pragma unroll
    for (int k1 = 0; k1 < 16; ++k1)
        w[k1] = cmul(v[REG(k1)], twl[16 * k1 + t]);   // * W256^{t*k1}
    #pragma unroll
    for (int k1 = 0; k1 < 16; ++k1)
        sp[16 * k1 + (t ^ k1)] = w[k1];               // M[k1][t]
    __syncthreads();
    #pragma unroll
    for (int n2 = 0; n2 < 16; ++n2)
        v[n2] = sp[16 * t + (n2 ^ t)];                // M[t][n2]
    fft16<false>(v);  // over n2 -> B[k2] = X[t + 16*k2] at v[REG(k2)]
    #pragma unroll
    for (int k2 = 0; k2 < 16; ++k2)
        w[k2] = cmul(v[REG(k2)], c2l[t + 16 * k2]);   // mid: * c2
    fft16<true>(w);   // over k2 -> C[m2] at w[REG(m2)]
    __syncthreads();  // all phase-1 reads done before overwrite
    #pragma unroll
    for (int m2 = 0; m2 < 16; ++m2) {
        float2 tw = twl[16 * m2 + t];
        tw.y = -tw.y;                                 // W256^{+t*m2}
        sp[16 * m2 + (t ^ m2)] = cmul(w[REG(m2)], tw);
    }
    __syncthreads();
    #pragma unroll
    for (int k1 = 0; k1 < 16; ++k1)
        v[k1] = sp[16 * t + (k1 ^ t)];
    fft16<true>(v);   // over k1 -> z[16*m1 + t] at v[REG(m1)]
}

// ---------------- K1: FRFT along H on REAL input x -> Y ----------------------
// 32 columns per block, 512 threads. Input staged via coalesced float4 loads
// into LDS dword slots (round 7's 16 stride-1KB gathers/thread were latency-
// bound); compute phase reads LDS.
__global__ __launch_bounds__(512, 4) void frft_cols_real(
        const float* __restrict__ x,
        const float* __restrict__ alpha_p,
        float2* __restrict__ Y) {
    __shared__ float2 s[32 * LSQ];                 // 65.8 KB
    __shared__ float2 c1l[256], c2l[256], twl[256];
    __shared__ float sscl;
    int tid = threadIdx.x;

    int blk = blockIdx.x;
    int w0 = (blk & 7) << 5;                       // 32-col tile
    long long bc = blk >> 3;
    const float* xb = x + (bc << 16) + w0;

    // issue coalesced loads first (latency overlapped by table compute)
    float4 xv[4];
    #pragma unroll
    for (int p = 0; p < 4; ++p) {
        int idx = tid + (p << 9);                  // 0..2047
        int row = idx >> 3, c4 = idx & 7;
        xv[p] = *(const float4*)(xb + row * W_N + (c4 << 2));
    }

    make_tables(tid, alpha_p, c1l, c2l, twl, &sscl);

    // stage tile into LDS (dword view of s)
    float* fs = (float*)s;
    #pragma unroll
    for (int p = 0; p < 4; ++p) {
        int idx = tid + (p << 9);
        int row = idx >> 3, c4 = idx & 7;
        fs[(4 * c4 + 0) * (2 * LSQ) + row] = xv[p].x;
        fs[(4 * c4 + 1) * (2 * LSQ) + row] = xv[p].y;
        fs[(4 * c4 + 2) * (2 * LSQ) + row] = xv[p].z;
        fs[(4 * c4 + 3) * (2 * LSQ) + row] = xv[p].w;
    }
    __syncthreads();

    int seq = tid & 31, t = tid >> 5;              // 32 seqs x 16 t-groups
    float xs[16];
    #pragma unroll
    for (int n1 = 0; n1 < 16; ++n1)
        xs[n1] = fs[seq * (2 * LSQ) + 16 * (n1 ^ 8) + t];  // ifftshift
    float scl_v = sscl;
    __syncthreads();                               // staging reads done before core writes

    float2 v[16];
    #pragma unroll
    for (int n1 = 0; n1 < 16; ++n1) {
        float2 c = c1l[16 * n1 + t];
        v[n1] = make_float2(xs[n1] * c.x, xs[n1] * c.y);
    }

    frft_core16(v, s + seq * LSQ, t, c2l, twl);

    float sc = scl_v * (1.0f / 256.0f);
    float2* Yb = Y + (bc << 16) + w0 + seq;
    #pragma unroll
    for (int m1 = 0; m1 < 16; ++m1) {
        float2 o = cmul(v[REG(m1)], c1l[16 * m1 + t]);
        Yb[(16 * (m1 ^ 8) + t) * W_N] = make_float2(o.x * sc, o.y * sc);  // fftshift
    }
}

// ---------------- K2: FRFT along W fused with mag/ang + MFMA 1x1 conv --------
// One block per (b,h): 512 threads = 32 channels x 16 element-groups.
// Conv = 256(pix) x 32(out) x 64(feat) GEMM via mfma_f32_16x16x32_f16:
// A[m=lane&15][k=(lane>>4)*8+j] from feat LDS (.x for k<32, .y for k>=32,
// same addresses); B[k][n]: n=lane&15, k=(lane>>4)*8+j from wmat (f16, exact
// for identity weights); D (col=lane&15, row=(lane>>4)*4+reg) transposed
// through reused LDS for coalesced float4 stores.
__device__ __forceinline__ float fast_atan2(float y, float x) {
    float ax = fabsf(x), ay = fabsf(y);
    float mx = fmaxf(ax, ay), mn = fminf(ax, ay);
    float z = mn * __builtin_amdgcn_rcpf(fmaxf(mx, 1e-37f));
    float z2 = z * z;
    float p = fmaf(z2, -0.01172120f, 0.05265332f);
    p = fmaf(z2, p, -0.11643287f);
    p = fmaf(z2, p, 0.19354346f);
    p = fmaf(z2, p, -0.33262347f);
    p = fmaf(z2, p, 0.99997726f);
    p = p * z;
    float r = (ay > ax) ? (1.5707963f - p) : p;
    r = (x < 0.0f) ? (3.14159265f - r) : r;
    return copysignf(r, y);
}

__global__ __launch_bounds__(512, 4) void frft_rows_conv(
        const float2* __restrict__ Y,
        const float* __restrict__ alpha_p,
        const float* __restrict__ wmat, float* __restrict__ out) {
    __shared__ float2 s[32 * LSQ];   // per-channel regions; ends as (mag,ang); reused for D
    __shared__ float2 c1l[256], c2l[256], twl[256];
    __shared__ float sscl;
    int tid = threadIdx.x;
    int t = tid & 15, ch = tid >> 4;  // seq's 16 t-threads within one wave

    int b = blockIdx.x >> 8, h = blockIdx.x & 255;
    const float2* xr = Y + (((long long)(b * C_N + ch)) << 16) + (h << 8);

    float2 v[16];
    #pragma unroll
    for (int n1 = 0; n1 < 16; ++n1)
        v[n1] = xr[16 * (n1 ^ 8) + t];   // ifftshift along W

    make_tables(tid, alpha_p, c1l, c2l, twl, &sscl);
    __syncthreads();                     // tables ready

    #pragma unroll
    for (int n1 = 0; n1 < 16; ++n1)
        v[n1] = cmul(v[n1], c1l[16 * n1 + t]);

    float2* sp = s + ch * LSQ;
    frft_core16(v, sp, t, c2l, twl);

    // Store (mag, ang/pi): same-wave WAR with core's final reads (all 16 t of
    // this seq are in one wave -> lockstep safe).
    float sc = sscl * (1.0f / 256.0f);
    #pragma unroll
    for (int m1 = 0; m1 < 16; ++m1) {
        float2 o = cmul(v[REG(m1)], c1l[16 * m1 + t]);
        float mg = sc * sqrtf(fmaf(o.x, o.x, o.y * o.y));
        float an = fast_atan2(o.y, o.x) * 0.31830988618f;
        sp[16 * (m1 ^ 8) + t] = make_float2(mg, an);   // index = final pixel w
    }
    __syncthreads();

    // ---- MFMA conv phase ----
    int lane = tid & 63, wv = tid >> 6;
    int q = lane >> 4, l15 = lane & 15;

    // B fragments from global (L2-hot 8KB), f16
    half8 bf[2][2];
    #pragma unroll
    for (int nt = 0; nt < 2; ++nt)
        #pragma unroll
        for (int kt = 0; kt < 2; ++kt) {
            const float* wp = wmat + (nt * 16 + l15) * 64 + kt * 32 + q * 8;
            float4 wa = *(const float4*)wp;
            float4 wb = *(const float4*)(wp + 4);
            bf[nt][kt][0] = (_Float16)wa.x; bf[nt][kt][1] = (_Float16)wa.y;
            bf[nt][kt][2] = (_Float16)wa.z; bf[nt][kt][3] = (_Float16)wa.w;
            bf[nt][kt][4] = (_Float16)wb.x; bf[nt][kt][5] = (_Float16)wb.y;
            bf[nt][kt][6] = (_Float16)wb.z; bf[nt][kt][7] = (_Float16)wb.w;
        }

    f32x4 acc[2][2];
    #pragma unroll
    for (int i = 0; i < 2; ++i)
        #pragma unroll
        for (int j = 0; j < 2; ++j)
            acc[i][j] = (f32x4){0.0f, 0.0f, 0.0f, 0.0f};

    #pragma unroll
    for (int mt2 = 0; mt2 < 2; ++mt2) {
        int mt = wv * 2 + mt2;
        int w = mt * 16 + l15;
        half8 am, aa;
        #pragma unroll
        for (int j = 0; j < 8; ++j) {
            float2 fv = s[(q * 8 + j) * LSQ + w];   // channel q*8+j at pixel w
            am[j] = (_Float16)fv.x;                 // mag -> k = q*8+j
            aa[j] = (_Float16)fv.y;                 // ang -> k = 32 + q*8+j
        }
        #pragma unroll
        for (int nt = 0; nt < 2; ++nt) {
            acc[mt2][nt] = __builtin_amdgcn_mfma_f32_16x16x32_f16(am, bf[nt][0], acc[mt2][nt], 0, 0, 0);
            acc[mt2][nt] = __builtin_amdgcn_mfma_f32_16x16x32_f16(aa, bf[nt][1], acc[mt2][nt], 0, 0, 0);
        }
    }
    __syncthreads();   // all feat reads done before D overwrites s

    // D -> LDS transpose buffer Ob[o][w]
    float* Ob = (float*)s;
    #pragma unroll
    for (int mt2 = 0; mt2 < 2; ++mt2) {
        int mt = wv * 2 + mt2;
        #pragma unroll
        for (int nt = 0; nt < 2; ++nt) {
            int o = nt * 16 + l15;
            *(f32x4*)&Ob[o * LDW + mt * 16 + q * 4] = acc[mt2][nt];
        }
    }
    __syncthreads();

    // coalesced stores: thread -> (o = tid>>4, 4 float4 chunks along w)
    int o2 = tid >> 4, i16 = tid & 15;
    float* ob = out + (((long long)(b * C_N + o2)) << 16) + (h << 8);
    #pragma unroll
    for (int p = 0; p < 4; ++p) {
        int w4 = i16 * 4 + (p << 6);
        f32x4 val = *(f32x4*)&Ob[o2 * LDW + w4];
        *(f32x4*)(ob + w4) = val;
    }
}

// ---------------- launch -----------------------------------------------------
extern "C" void kernel_launch(void* const* d_in, const int* in_sizes, int n_in,
                              void* d_out, int out_size, void* d_ws, size_t ws_size,
                              hipStream_t stream) {
    const float* x     = (const float*)d_in[0];
    const float* alpha = (const float*)d_in[1];
    const float* wmat  = (const float*)d_in[2];
    float* out = (float*)d_out;

    float2* Y = (float2*)d_ws;   // 64 MiB intermediate (H-pass output)

    // Pass 1: FRFT along H on real input (order commutes with W pass).
    frft_cols_real<<<B_N * C_N * (W_N / 32), 512, 0, stream>>>(x, alpha, Y);

    // Pass 2: FRFT along W + magnitude/phase + MFMA 1x1 conv, fused per (b,h).
    frft_rows_conv<<<B_N * H_N, 512, 0, stream>>>(Y, alpha, wmat, out);
}